// Round 5
// baseline (473.793 us; speedup 1.0000x reference)
//
#include <hip/hip_runtime.h>

// ---------------------------------------------------------------------------
// PEPS 4x5, D=4, P=2, depth-5 gate sweeps, 64-point gather.
// psi kept in COLUMN-major qubit order: qubit (i,j) at bit (19 - 4*j - i).
// ---------------------------------------------------------------------------

#define PAD(i) ((i) + (((i) >> 4) << 2))   // +4 floats per 16 -> LDS bank spread
#define PIDX(i,j,p,u,d,l,r) (((((((i)*5+(j))*2+(p))*4+(u))*4+(d))*4+(l))*4+(r))

// workspace float offsets
static constexpr int COL0  = 0;                    // [16][256]
static constexpr int COL1  = 4096;                 // [16][256][256]
static constexpr int COL2  = COL1 + 1048576;
static constexpr int COL3  = COL2 + 1048576;
static constexpr int COL4  = COL3 + 1048576;       // [16][256]
static constexpr int M01TO = COL4 + 4096;          // [c01=256][R2=256]
static constexpr int M34TO = M01TO + 65536;        // [L3=256][c34=256]
static constexpr int T12TO = M34TO + 65536;        // [c2=16][c01=256][R3=256]
static constexpr int PSIO  = T12TO + 1048576;      // [2^20]

// --------------------------- column tensors --------------------------------
__global__ __launch_bounds__(256) void k_build_cols(const float* __restrict__ peps,
                                                    float* __restrict__ ws) {
  __shared__ float p01[4096], p23[4096];
  int bid = blockIdx.x, t = threadIdx.x;
  if (bid < 384) {
    int col = 1 + (bid >> 7);
    int part = bid & 127;
#pragma unroll
    for (int k = 0; k < 16; ++k) {
      int e = k * 256 + t;
      int r12 = e & 15, l12 = (e >> 4) & 15, d2 = (e >> 8) & 3, p = e >> 10;
      int l1 = l12 >> 2, l2 = l12 & 3, r1 = r12 >> 2, r2 = r12 & 3;
      float s01 = 0.f, s23 = 0.f;
#pragma unroll
      for (int d = 0; d < 4; ++d) {
        s01 += peps[PIDX(0, col, (p >> 1), 0, d, l1, r1)] *
               peps[PIDX(1, col, (p & 1), d, d2, l2, r2)];
        s23 += peps[PIDX(2, col, (p >> 1), d2, d, l1, r1)] *
               peps[PIDX(3, col, (p & 1), d, 0, l2, r2)];
      }
      p01[e] = s01;
      p23[e] = s23;
    }
    __syncthreads();
    const int coloffs[3] = {COL1, COL2, COL3};
    float* out = ws + coloffs[col - 1];
#pragma unroll
    for (int k = 0; k < 8; ++k) {
      int eq = part * 8192 + (k * 256 + t) * 4;
      int r34b = eq & 15;
      int r12 = (eq >> 4) & 15, l34 = (eq >> 8) & 15, l12 = (eq >> 12) & 15;
      int p = eq >> 16;
      int pa = p >> 2, pb = p & 3;
      float4 acc = {0.f, 0.f, 0.f, 0.f};
#pragma unroll
      for (int d2 = 0; d2 < 4; ++d2) {
        float a01 = p01[((((pa * 4 + d2) << 4) | l12) << 4) | r12];
        const float4 b4 =
            *(const float4*)&p23[((((pb * 4 + d2) << 4) | l34) << 4) | r34b];
        acc.x += a01 * b4.x;
        acc.y += a01 * b4.y;
        acc.z += a01 * b4.z;
        acc.w += a01 * b4.w;
      }
      *(float4*)&out[eq] = acc;
    }
  } else {
    int col = (bid == 384) ? 0 : 4;
    const int lsh = (col == 0) ? 0 : 2;
    const int rsh = (col == 4) ? 0 : 2;
    const int ldim = 1 << lsh, rdim = 1 << rsh;
    const int LLB = 2 * lsh, RRB = 2 * rsh;
    const int LL = 1 << LLB, RR = 1 << RRB;
    int n12 = (LL * RR) << 4;
    for (int e = t; e < n12; e += 256) {
      int r12 = e & (RR - 1);
      int l12 = (e >> RRB) & (LL - 1);
      int d2 = (e >> (RRB + LLB)) & 3;
      int p = e >> (RRB + LLB + 2);
      int l1 = l12 >> lsh, l2 = l12 & (ldim - 1);
      int r1 = r12 >> rsh, r2 = r12 & (rdim - 1);
      float s01 = 0.f, s23 = 0.f;
      for (int d = 0; d < 4; ++d) {
        s01 += peps[PIDX(0, col, (p >> 1), 0, d, l1, r1)] *
               peps[PIDX(1, col, (p & 1), d, d2, l2, r2)];
        s23 += peps[PIDX(2, col, (p >> 1), d2, d, l1, r1)] *
               peps[PIDX(3, col, (p & 1), d, 0, l2, r2)];
      }
      p01[e] = s01;
      p23[e] = s23;
    }
    __syncthreads();
    const int LB = 2 * LLB, RB = 2 * RRB;
    int total = 16 << (LB + RB);  // 4096
    float* out = ws + ((col == 0) ? COL0 : COL4);
    for (int e = t; e < total; e += 256) {
      int r = e & ((1 << RB) - 1);
      int l = (e >> RB) & ((1 << LB) - 1);
      int p = e >> (RB + LB);
      int r34 = r & (RR - 1), r12 = r >> RRB;
      int l34 = l & (LL - 1), l12 = l >> LLB;
      int pa = p >> 2, pb = p & 3;
      float s = 0.f;
      for (int d2 = 0; d2 < 4; ++d2) {
        s += p01[((((pa * 4 + d2) << LLB) | l12) << RRB) | r12] *
             p23[((((pb * 4 + d2) << LLB) | l34) << RRB) | r34];
      }
      out[e] = s;
    }
  }
}

// ------------------- M01 / M34T (edge-pair contractions) -------------------
// blocks 0..63: M01[c01][R2] = sum_R1 Col0[c0,R1]*Col1[c1,R1,R2]
//   block = (c1, R2-quarter); col1 streamed exactly once overall.
// blocks 64..319: M34T[L3][c34] = sum_B Col3[c3,L3,B]*Col4[c4,B]
__global__ __launch_bounds__(256) void k_small(const float* __restrict__ ws,
                                               float* __restrict__ m01,
                                               float* __restrict__ m34t) {
  __shared__ float c3buf[4112], c4buf[4112];
  int t = threadIdx.x;
  if (blockIdx.x < 64) {
    int c1 = blockIdx.x >> 2, q = blockIdx.x & 3;
    int r2l = t & 63, c0g = t >> 6;  // wave-uniform c0 group (4 c0 each)
    int R2 = q * 64 + r2l;
    const float* col0 = ws + COL0;
    const float* col1 = ws + COL1;
    float a0 = 0.f, a1 = 0.f, a2 = 0.f, a3 = 0.f;
    for (int R1 = 0; R1 < 256; ++R1) {
      float bv = col1[(c1 * 256 + R1) * 256 + R2];  // coalesced
      a0 += col0[(c0g * 4 + 0) * 256 + R1] * bv;    // uniform -> s_load
      a1 += col0[(c0g * 4 + 1) * 256 + R1] * bv;
      a2 += col0[(c0g * 4 + 2) * 256 + R1] * bv;
      a3 += col0[(c0g * 4 + 3) * 256 + R1] * bv;
    }
    m01[((c0g * 4 + 0) * 16 + c1) * 256 + R2] = a0;  // coalesced
    m01[((c0g * 4 + 1) * 16 + c1) * 256 + R2] = a1;
    m01[((c0g * 4 + 2) * 16 + c1) * 256 + R2] = a2;
    m01[((c0g * 4 + 3) * 16 + c1) * 256 + R2] = a3;
  } else {
    int L3 = blockIdx.x - 64;  // 0..255
    const float* col3 = ws + COL3;
    const float* col4 = ws + COL4;
    for (int e = t; e < 4096; e += 256) {
      c4buf[(e >> 8) * 257 + (e & 255)] = col4[e];
      c3buf[(e >> 8) * 257 + (e & 255)] =
          col3[(e >> 8) * 65536 + L3 * 256 + (e & 255)];
    }
    __syncthreads();
    int c3 = t >> 4, c4 = t & 15;
    float acc = 0.f;
    for (int B = 0; B < 256; ++B)
      acc += c3buf[c3 * 257 + B] * c4buf[c4 * 257 + B];
    m34t[L3 * 256 + t] = acc;
  }
}

// ---------------- T012[c2][c01][R3] = M01 x Col2 ---------------------------
__global__ __launch_bounds__(256) void k_t012(const float* __restrict__ m01,
                                              const float* __restrict__ col2,
                                              float* __restrict__ t012) {
  int t = threadIdx.x;            // R3
  int c2 = blockIdx.x & 15, tg = blockIdx.x >> 4;
  float acc[16] = {};
  for (int R2 = 0; R2 < 256; ++R2) {
    float bv = col2[c2 * 65536 + R2 * 256 + t];  // coalesced
#pragma unroll
    for (int i = 0; i < 16; ++i)
      acc[i] += m01[(tg * 16 + i) * 256 + R2] * bv;  // uniform -> s_load
  }
#pragma unroll
  for (int i = 0; i < 16; ++i)
    t012[c2 * 65536 + (tg * 16 + i) * 256 + t] = acc[i];  // coalesced
}

// ---------------- psi = T012 x M34T  (psi[P012*256 + c34]) -----------------
// P012 row r = c01*16 + c2; block tg = c01, i = c2.
__global__ __launch_bounds__(256) void k_psi0(const float* __restrict__ t012,
                                              const float* __restrict__ m34t,
                                              float* __restrict__ psi) {
  int t = threadIdx.x;  // c34
  int tg = blockIdx.x;  // c01
  float acc[16] = {};
  for (int L3 = 0; L3 < 256; ++L3) {
    float bv = m34t[L3 * 256 + t];  // coalesced
#pragma unroll
    for (int i = 0; i < 16; ++i)
      acc[i] += t012[i * 65536 + tg * 256 + L3] * bv;  // uniform -> s_load
  }
#pragma unroll
  for (int i = 0; i < 16; ++i)
    psi[(tg * 16 + i) * 256 + t] = acc[i];  // coalesced
}

// ---------------- register-level 2-qubit gate ------------------------------
template <int NB, int HI, int LO>
__device__ __forceinline__ void gate2(float* x, const float* __restrict__ g) {
  constexpr int H = 1 << HI, L = 1 << LO, N = 1 << NB;
#pragma unroll
  for (int o = 0; o < N; ++o) {
    if (o & (H | L)) continue;
    float v0 = x[o], v1 = x[o + L], v2 = x[o + H], v3 = x[o + H + L];
    x[o]         = g[0]  * v0 + g[1]  * v1 + g[2]  * v2 + g[3]  * v3;
    x[o + L]     = g[4]  * v0 + g[5]  * v1 + g[6]  * v2 + g[7]  * v3;
    x[o + H]     = g[8]  * v0 + g[9]  * v1 + g[10] * v2 + g[11] * v3;
    x[o + H + L] = g[12] * v0 + g[13] * v1 + g[14] * v2 + g[15] * v3;
  }
}

// H row transform: 5-bit group (bit4 = leftmost column), bonds j: (4-j,3-j)
template <int S4, int S3, int S2, int S1, int S0>
__device__ __forceinline__ void hxf(float* s, const float* __restrict__ g, int b) {
  float x[32];
#pragma unroll
  for (int m = 0; m < 32; ++m) {
    int off = ((m >> 4) & 1) * S4 + ((m >> 3) & 1) * S3 + ((m >> 2) & 1) * S2 +
              ((m >> 1) & 1) * S1 + (m & 1) * S0;
    x[m] = s[PAD(b + off)];
  }
  gate2<5, 4, 3>(x, g);
  gate2<5, 3, 2>(x, g);
  gate2<5, 2, 1>(x, g);
  gate2<5, 1, 0>(x, g);
#pragma unroll
  for (int m = 0; m < 32; ++m) {
    int off = ((m >> 4) & 1) * S4 + ((m >> 3) & 1) * S3 + ((m >> 2) & 1) * S2 +
              ((m >> 1) & 1) * S1 + (m & 1) * S0;
    s[PAD(b + off)] = x[m];
  }
}

// V column transform: 4-bit nibble (bit3 = row 0), bonds i: (3-i,2-i)
template <int ST>
__device__ __forceinline__ void vxf(float* s, const float* __restrict__ g, int b) {
  float x[16];
#pragma unroll
  for (int m = 0; m < 16; ++m) x[m] = s[PAD(b + m * ST)];
  gate2<4, 3, 2>(x, g);
  gate2<4, 2, 1>(x, g);
  gate2<4, 1, 0>(x, g);
#pragma unroll
  for (int m = 0; m < 16; ++m) s[PAD(b + m * ST)] = x[m];
}

// H phase A: rows 2,3 ; slab bits {17,16,13,12,9,8,5..0}
__global__ __launch_bounds__(256) void k_ha(float* __restrict__ psi,
                                            const float* __restrict__ gate) {
  __shared__ float s[5120];
  float g[16];
#pragma unroll
  for (int i = 0; i < 16; ++i) g[i] = gate[i];
  int t = threadIdx.x;  // 256
  int o = blockIdx.x;   // outer bits {19,18,15,14,11,10,7,6}
  int base = ((o >> 6) & 3) * 262144 + ((o >> 4) & 3) * 16384 +
             ((o >> 2) & 3) * 1024 + (o & 3) * 64;
#pragma unroll
  for (int i = 0; i < 4; ++i) {
    int f = (i * 256 + t) * 4;
    int w = f & 63, c = (f >> 6) & 3, b = (f >> 8) & 3, a = (f >> 10) & 3;
    *(float4*)(s + PAD(f)) =
        *(const float4*)(psi + base + a * 65536 + b * 4096 + c * 256 + w);
  }
  __syncthreads();
  if (t < 128) {  // row 2: slab bits {11,9,7,5,1}
    int b2 = ((t >> 6) & 1) * 1024 + ((t >> 5) & 1) * 256 + ((t >> 4) & 1) * 64 +
             ((t >> 3) & 1) * 16 + ((t >> 2) & 1) * 8 + ((t >> 1) & 1) * 4 + (t & 1);
    hxf<2048, 512, 128, 32, 2>(s, g, b2);
  }
  __syncthreads();
  if (t < 128) {  // row 3: slab bits {10,8,6,4,0}
    int b3 = ((t >> 6) & 1) * 2048 + ((t >> 5) & 1) * 512 + ((t >> 4) & 1) * 128 +
             ((t >> 3) & 1) * 32 + ((t & 7) << 1);
    hxf<1024, 256, 64, 16, 1>(s, g, b3);
  }
  __syncthreads();
#pragma unroll
  for (int i = 0; i < 4; ++i) {
    int f = (i * 256 + t) * 4;
    int w = f & 63, c = (f >> 6) & 3, b = (f >> 8) & 3, a = (f >> 10) & 3;
    *(float4*)(psi + base + a * 65536 + b * 4096 + c * 256 + w) =
        *(const float4*)(s + PAD(f));
  }
}

// H phase B: rows 0,1 + V col 4 ; slab bits {19,18,15,14,11,10,7,6,3..0}
__global__ __launch_bounds__(256) void k_hb(float* __restrict__ psi,
                                            const float* __restrict__ gate) {
  __shared__ float s[5120];
  float g[16];
#pragma unroll
  for (int i = 0; i < 16; ++i) g[i] = gate[i];
  int t = threadIdx.x;  // 256
  int o = blockIdx.x;   // outer bits {17,16,13,12,9,8,5,4}
  int base = ((o >> 6) & 3) * 65536 + ((o >> 4) & 3) * 4096 +
             ((o >> 2) & 3) * 256 + (o & 3) * 16;
#pragma unroll
  for (int i = 0; i < 4; ++i) {
    int f = (i * 256 + t) * 4;
    int w = f & 15, d = (f >> 4) & 3, c = (f >> 6) & 3, b = (f >> 8) & 3,
        a = (f >> 10) & 3;
    *(float4*)(s + PAD(f)) = *(const float4*)(psi + base + a * 262144 +
                                              b * 16384 + c * 1024 + d * 64 + w);
  }
  __syncthreads();
  if (t < 128) {  // row 0: slab bits {11,9,7,5,3}
    int b0 = ((t >> 6) & 1) * 1024 + ((t >> 5) & 1) * 256 + ((t >> 4) & 1) * 64 +
             ((t >> 3) & 1) * 16 + ((t >> 2) & 1) * 4 + (t & 3);
    hxf<2048, 512, 128, 32, 8>(s, g, b0);
  }
  __syncthreads();
  if (t < 128) {  // row 1: slab bits {10,8,6,4,2}
    int b1 = ((t >> 6) & 1) * 2048 + ((t >> 5) & 1) * 512 + ((t >> 4) & 1) * 128 +
             ((t >> 3) & 1) * 32 + ((t >> 2) & 1) * 8 + (t & 3);
    hxf<1024, 256, 64, 16, 4>(s, g, b1);
  }
  __syncthreads();
  // V col 4 (slab bits 3..0): all H for col-4 qubits is complete here.
  vxf<1>(s, g, t * 16);
  __syncthreads();
#pragma unroll
  for (int i = 0; i < 4; ++i) {
    int f = (i * 256 + t) * 4;
    int w = f & 15, d = (f >> 4) & 3, c = (f >> 6) & 3, b = (f >> 8) & 3,
        a = (f >> 10) & 3;
    *(float4*)(psi + base + a * 262144 + b * 16384 + c * 1024 + d * 64 + w) =
        *(const float4*)(s + PAD(f));
  }
}

// V phase A: cols c2,c3 (bits 11..4; slab bits 11..0)
__global__ __launch_bounds__(256) void k_va(float* __restrict__ psi,
                                            const float* __restrict__ gate) {
  __shared__ float s[5120];
  float g[16];
#pragma unroll
  for (int i = 0; i < 16; ++i) g[i] = gate[i];
  int t = threadIdx.x;
  int base = blockIdx.x * 4096;
#pragma unroll
  for (int i = 0; i < 4; ++i) {
    int f = (i * 256 + t) * 4;
    *(float4*)(s + PAD(f)) = *(const float4*)(psi + base + f);
  }
  __syncthreads();
  vxf<16>(s, g, ((t >> 4) << 8) | (t & 15));     // c3
  __syncthreads();
  vxf<256>(s, g, t);                             // c2
  __syncthreads();
#pragma unroll
  for (int i = 0; i < 4; ++i) {
    int f = (i * 256 + t) * 4;
    *(float4*)(psi + base + f) = *(const float4*)(s + PAD(f));
  }
}

// V phase B: cols c0,c1 (bits 19..12) ; slab bits {19..12, 3..0}
// GATHER=true on the final iteration: each block emits outputs in its slab.
template <bool GATHER>
__global__ __launch_bounds__(256) void k_vb(float* __restrict__ psi,
                                            const float* __restrict__ gate,
                                            const int* __restrict__ x,
                                            float* __restrict__ out) {
  __shared__ float s[5120];
  float g[16];
#pragma unroll
  for (int i = 0; i < 16; ++i) g[i] = gate[i];
  int t = threadIdx.x;
  int o = blockIdx.x;  // bits 11..4
#pragma unroll
  for (int i = 0; i < 4; ++i) {
    int f = (i * 256 + t) * 4;
    int h = f >> 4, w = f & 15;
    *(float4*)(s + PAD(f)) = *(const float4*)(psi + h * 4096 + o * 16 + w);
  }
  __syncthreads();
  vxf<256>(s, g, t);                             // c0 (slab bits 11..8)
  __syncthreads();
  vxf<16>(s, g, ((t >> 4) << 8) | (t & 15));     // c1 (slab bits 7..4)
  __syncthreads();
  if (GATHER && t < 64) {
    int idx = 0;
#pragma unroll
    for (int q = 0; q < 20; ++q) {
      int i = q / 5, j = q % 5;
      idx |= x[t * 20 + q] << (19 - 4 * j - i);
    }
    if (((idx >> 4) & 255) == o)
      out[t] = s[PAD(((idx >> 12) << 4) | (idx & 15))];
  }
#pragma unroll
  for (int i = 0; i < 4; ++i) {
    int f = (i * 256 + t) * 4;
    int h = f >> 4, w = f & 15;
    *(float4*)(psi + h * 4096 + o * 16 + w) = *(const float4*)(s + PAD(f));
  }
}

// ---------------------------------------------------------------------------
extern "C" void kernel_launch(void* const* d_in, const int* in_sizes, int n_in,
                              void* d_out, int out_size, void* d_ws, size_t ws_size,
                              hipStream_t stream) {
  const int* x = (const int*)d_in[0];
  const float* peps = (const float*)d_in[1];
  const float* gate = (const float*)d_in[2];
  float* ws = (float*)d_ws;
  float* psi = ws + PSIO;
  float* out = (float*)d_out;

  k_build_cols<<<386, 256, 0, stream>>>(peps, ws);
  k_small<<<320, 256, 0, stream>>>(ws, ws + M01TO, ws + M34TO);
  k_t012<<<256, 256, 0, stream>>>(ws + M01TO, ws + COL2, ws + T12TO);
  k_psi0<<<256, 256, 0, stream>>>(ws + T12TO, ws + M34TO, psi);
  for (int it = 0; it < 5; ++it) {
    k_ha<<<256, 256, 0, stream>>>(psi, gate);
    k_hb<<<256, 256, 0, stream>>>(psi, gate);
    k_va<<<256, 256, 0, stream>>>(psi, gate);
    if (it < 4)
      k_vb<false><<<256, 256, 0, stream>>>(psi, gate, x, out);
    else
      k_vb<true><<<256, 256, 0, stream>>>(psi, gate, x, out);
  }
}

// Round 6
// 270.382 us; speedup vs baseline: 1.7523x; 1.7523x over previous
//
#include <hip/hip_runtime.h>

// ---------------------------------------------------------------------------
// PEPS 4x5, D=4, P=2, depth-5 gate sweeps, 64-point gather.
// psi kept in COLUMN-major qubit order: qubit (i,j) at bit (19 - 4*j - i).
// GEMM kernels stage the 16KB A-operand in LDS (broadcast b128 reads) --
// uniform global reads via s_load proved fragile (R5: 194us k_psi0).
// ---------------------------------------------------------------------------

#define PAD(i) ((i) + (((i) >> 4) << 2))   // +4 floats per 16 -> LDS bank spread
#define PIDX(i,j,p,u,d,l,r) (((((((i)*5+(j))*2+(p))*4+(u))*4+(d))*4+(l))*4+(r))

// workspace float offsets
static constexpr int COL0  = 0;                    // [16][256]
static constexpr int COL1  = 4096;                 // [16][256][256]
static constexpr int COL2  = COL1 + 1048576;
static constexpr int COL3  = COL2 + 1048576;
static constexpr int COL4  = COL3 + 1048576;       // [16][256]
static constexpr int M01TO = COL4 + 4096;          // [c01=256][R2=256]
static constexpr int M34TO = M01TO + 65536;        // [L3=256][c34=256]
static constexpr int T12TO = M34TO + 65536;        // [c2=16][c01=256][R3=256]
static constexpr int PSIO  = T12TO + 1048576;      // [2^20]

// --------------------------- column tensors --------------------------------
__global__ __launch_bounds__(256) void k_build_cols(const float* __restrict__ peps,
                                                    float* __restrict__ ws) {
  __shared__ float p01[4096], p23[4096];
  int bid = blockIdx.x, t = threadIdx.x;
  if (bid < 384) {
    int col = 1 + (bid >> 7);
    int part = bid & 127;
#pragma unroll
    for (int k = 0; k < 16; ++k) {
      int e = k * 256 + t;
      int r12 = e & 15, l12 = (e >> 4) & 15, d2 = (e >> 8) & 3, p = e >> 10;
      int l1 = l12 >> 2, l2 = l12 & 3, r1 = r12 >> 2, r2 = r12 & 3;
      float s01 = 0.f, s23 = 0.f;
#pragma unroll
      for (int d = 0; d < 4; ++d) {
        s01 += peps[PIDX(0, col, (p >> 1), 0, d, l1, r1)] *
               peps[PIDX(1, col, (p & 1), d, d2, l2, r2)];
        s23 += peps[PIDX(2, col, (p >> 1), d2, d, l1, r1)] *
               peps[PIDX(3, col, (p & 1), d, 0, l2, r2)];
      }
      p01[e] = s01;
      p23[e] = s23;
    }
    __syncthreads();
    const int coloffs[3] = {COL1, COL2, COL3};
    float* out = ws + coloffs[col - 1];
#pragma unroll
    for (int k = 0; k < 8; ++k) {
      int eq = part * 8192 + (k * 256 + t) * 4;
      int r34b = eq & 15;
      int r12 = (eq >> 4) & 15, l34 = (eq >> 8) & 15, l12 = (eq >> 12) & 15;
      int p = eq >> 16;
      int pa = p >> 2, pb = p & 3;
      float4 acc = {0.f, 0.f, 0.f, 0.f};
#pragma unroll
      for (int d2 = 0; d2 < 4; ++d2) {
        float a01 = p01[((((pa * 4 + d2) << 4) | l12) << 4) | r12];
        const float4 b4 =
            *(const float4*)&p23[((((pb * 4 + d2) << 4) | l34) << 4) | r34b];
        acc.x += a01 * b4.x;
        acc.y += a01 * b4.y;
        acc.z += a01 * b4.z;
        acc.w += a01 * b4.w;
      }
      *(float4*)&out[eq] = acc;
    }
  } else {
    int col = (bid == 384) ? 0 : 4;
    const int lsh = (col == 0) ? 0 : 2;
    const int rsh = (col == 4) ? 0 : 2;
    const int ldim = 1 << lsh, rdim = 1 << rsh;
    const int LLB = 2 * lsh, RRB = 2 * rsh;
    const int LL = 1 << LLB, RR = 1 << RRB;
    int n12 = (LL * RR) << 4;
    for (int e = t; e < n12; e += 256) {
      int r12 = e & (RR - 1);
      int l12 = (e >> RRB) & (LL - 1);
      int d2 = (e >> (RRB + LLB)) & 3;
      int p = e >> (RRB + LLB + 2);
      int l1 = l12 >> lsh, l2 = l12 & (ldim - 1);
      int r1 = r12 >> rsh, r2 = r12 & (rdim - 1);
      float s01 = 0.f, s23 = 0.f;
      for (int d = 0; d < 4; ++d) {
        s01 += peps[PIDX(0, col, (p >> 1), 0, d, l1, r1)] *
               peps[PIDX(1, col, (p & 1), d, d2, l2, r2)];
        s23 += peps[PIDX(2, col, (p >> 1), d2, d, l1, r1)] *
               peps[PIDX(3, col, (p & 1), d, 0, l2, r2)];
      }
      p01[e] = s01;
      p23[e] = s23;
    }
    __syncthreads();
    const int LB = 2 * LLB, RB = 2 * RRB;
    int total = 16 << (LB + RB);  // 4096
    float* out = ws + ((col == 0) ? COL0 : COL4);
    for (int e = t; e < total; e += 256) {
      int r = e & ((1 << RB) - 1);
      int l = (e >> RB) & ((1 << LB) - 1);
      int p = e >> (RB + LB);
      int r34 = r & (RR - 1), r12 = r >> RRB;
      int l34 = l & (LL - 1), l12 = l >> LLB;
      int pa = p >> 2, pb = p & 3;
      float s = 0.f;
      for (int d2 = 0; d2 < 4; ++d2) {
        s += p01[((((pa * 4 + d2) << LLB) | l12) << RRB) | r12] *
             p23[((((pb * 4 + d2) << LLB) | l34) << RRB) | r34];
      }
      out[e] = s;
    }
  }
}

// ------------------- M01 / M34T (edge-pair contractions) -------------------
__global__ __launch_bounds__(256) void k_small(const float* __restrict__ ws,
                                               float* __restrict__ m01,
                                               float* __restrict__ m34t) {
  __shared__ float c3buf[4112], c4buf[4112];
  int t = threadIdx.x;
  if (blockIdx.x < 64) {
    int c1 = blockIdx.x >> 2, q = blockIdx.x & 3;
    int r2l = t & 63, c0g = t >> 6;  // wave-uniform c0 group (4 c0 each)
    int R2 = q * 64 + r2l;
    const float* col0 = ws + COL0;
    const float* col1 = ws + COL1;
    float a0 = 0.f, a1 = 0.f, a2 = 0.f, a3 = 0.f;
    for (int R1 = 0; R1 < 256; ++R1) {
      float bv = col1[(c1 * 256 + R1) * 256 + R2];  // coalesced
      a0 += col0[(c0g * 4 + 0) * 256 + R1] * bv;    // uniform -> s_load
      a1 += col0[(c0g * 4 + 1) * 256 + R1] * bv;
      a2 += col0[(c0g * 4 + 2) * 256 + R1] * bv;
      a3 += col0[(c0g * 4 + 3) * 256 + R1] * bv;
    }
    m01[((c0g * 4 + 0) * 16 + c1) * 256 + R2] = a0;  // coalesced
    m01[((c0g * 4 + 1) * 16 + c1) * 256 + R2] = a1;
    m01[((c0g * 4 + 2) * 16 + c1) * 256 + R2] = a2;
    m01[((c0g * 4 + 3) * 16 + c1) * 256 + R2] = a3;
  } else {
    int L3 = blockIdx.x - 64;  // 0..255
    const float* col3 = ws + COL3;
    const float* col4 = ws + COL4;
    for (int e = t; e < 4096; e += 256) {
      c4buf[(e >> 8) * 257 + (e & 255)] = col4[e];
      c3buf[(e >> 8) * 257 + (e & 255)] =
          col3[(e >> 8) * 65536 + L3 * 256 + (e & 255)];
    }
    __syncthreads();
    int c3 = t >> 4, c4 = t & 15;
    float acc = 0.f;
    for (int B = 0; B < 256; ++B)
      acc += c3buf[c3 * 257 + B] * c4buf[c4 * 257 + B];
    m34t[L3 * 256 + t] = acc;
  }
}

// ---------------- T012[c2][c01][R3] = M01 x Col2 ---------------------------
// A-tile (m01 rows tg*16..+15, 16KB contiguous) staged in LDS.
__global__ __launch_bounds__(256) void k_t012(const float* __restrict__ m01,
                                              const float* __restrict__ col2,
                                              float* __restrict__ t012) {
  __shared__ float A[4096];  // [i=16][R2=256]
  int t = threadIdx.x;       // R3
  int c2 = blockIdx.x & 15, tg = blockIdx.x >> 4;
#pragma unroll
  for (int k = 0; k < 4; ++k)
    *(float4*)&A[(k * 256 + t) * 4] =
        *(const float4*)&m01[tg * 4096 + (k * 256 + t) * 4];
  __syncthreads();
  float acc[16] = {};
  for (int R2 = 0; R2 < 256; R2 += 4) {
    float b0 = col2[c2 * 65536 + (R2 + 0) * 256 + t];
    float b1 = col2[c2 * 65536 + (R2 + 1) * 256 + t];
    float b2 = col2[c2 * 65536 + (R2 + 2) * 256 + t];
    float b3 = col2[c2 * 65536 + (R2 + 3) * 256 + t];
#pragma unroll
    for (int i = 0; i < 16; ++i) {
      float4 a4 = *(const float4*)&A[i * 256 + R2];  // broadcast b128
      acc[i] += a4.x * b0 + a4.y * b1 + a4.z * b2 + a4.w * b3;
    }
  }
#pragma unroll
  for (int i = 0; i < 16; ++i)
    t012[c2 * 65536 + (tg * 16 + i) * 256 + t] = acc[i];  // coalesced
}

// ---------------- psi = T012 x M34T  (psi[(c01*16+c2)*256 + c34]) ----------
__global__ __launch_bounds__(256) void k_psi0(const float* __restrict__ t012,
                                              const float* __restrict__ m34t,
                                              float* __restrict__ psi) {
  __shared__ float A[4096];  // [i=c2=16][L3=256]
  int t = threadIdx.x;       // c34 (and L3 for staging)
  int tg = blockIdx.x;       // c01
#pragma unroll
  for (int i = 0; i < 16; ++i)
    A[i * 256 + t] = t012[i * 65536 + tg * 256 + t];  // coalesced 1KB chunks
  __syncthreads();
  float acc[16] = {};
  for (int L3 = 0; L3 < 256; L3 += 4) {
    float b0 = m34t[(L3 + 0) * 256 + t];
    float b1 = m34t[(L3 + 1) * 256 + t];
    float b2 = m34t[(L3 + 2) * 256 + t];
    float b3 = m34t[(L3 + 3) * 256 + t];
#pragma unroll
    for (int i = 0; i < 16; ++i) {
      float4 a4 = *(const float4*)&A[i * 256 + L3];  // broadcast b128
      acc[i] += a4.x * b0 + a4.y * b1 + a4.z * b2 + a4.w * b3;
    }
  }
#pragma unroll
  for (int i = 0; i < 16; ++i)
    psi[(tg * 16 + i) * 256 + t] = acc[i];  // coalesced
}

// ---------------- register-level 2-qubit gate ------------------------------
template <int NB, int HI, int LO>
__device__ __forceinline__ void gate2(float* x, const float* __restrict__ g) {
  constexpr int H = 1 << HI, L = 1 << LO, N = 1 << NB;
#pragma unroll
  for (int o = 0; o < N; ++o) {
    if (o & (H | L)) continue;
    float v0 = x[o], v1 = x[o + L], v2 = x[o + H], v3 = x[o + H + L];
    x[o]         = g[0]  * v0 + g[1]  * v1 + g[2]  * v2 + g[3]  * v3;
    x[o + L]     = g[4]  * v0 + g[5]  * v1 + g[6]  * v2 + g[7]  * v3;
    x[o + H]     = g[8]  * v0 + g[9]  * v1 + g[10] * v2 + g[11] * v3;
    x[o + H + L] = g[12] * v0 + g[13] * v1 + g[14] * v2 + g[15] * v3;
  }
}

// H row transform: 5-bit group (bit4 = leftmost column), bonds j: (4-j,3-j)
template <int S4, int S3, int S2, int S1, int S0>
__device__ __forceinline__ void hxf(float* s, const float* __restrict__ g, int b) {
  float x[32];
#pragma unroll
  for (int m = 0; m < 32; ++m) {
    int off = ((m >> 4) & 1) * S4 + ((m >> 3) & 1) * S3 + ((m >> 2) & 1) * S2 +
              ((m >> 1) & 1) * S1 + (m & 1) * S0;
    x[m] = s[PAD(b + off)];
  }
  gate2<5, 4, 3>(x, g);
  gate2<5, 3, 2>(x, g);
  gate2<5, 2, 1>(x, g);
  gate2<5, 1, 0>(x, g);
#pragma unroll
  for (int m = 0; m < 32; ++m) {
    int off = ((m >> 4) & 1) * S4 + ((m >> 3) & 1) * S3 + ((m >> 2) & 1) * S2 +
              ((m >> 1) & 1) * S1 + (m & 1) * S0;
    s[PAD(b + off)] = x[m];
  }
}

// V column transform: 4-bit nibble (bit3 = row 0), bonds i: (3-i,2-i)
template <int ST>
__device__ __forceinline__ void vxf(float* s, const float* __restrict__ g, int b) {
  float x[16];
#pragma unroll
  for (int m = 0; m < 16; ++m) x[m] = s[PAD(b + m * ST)];
  gate2<4, 3, 2>(x, g);
  gate2<4, 2, 1>(x, g);
  gate2<4, 1, 0>(x, g);
#pragma unroll
  for (int m = 0; m < 16; ++m) s[PAD(b + m * ST)] = x[m];
}

// H phase A: rows 2,3 ; slab bits {17,16,13,12,9,8,5..0}
__global__ __launch_bounds__(256) void k_ha(float* __restrict__ psi,
                                            const float* __restrict__ gate) {
  __shared__ float s[5120];
  float g[16];
#pragma unroll
  for (int i = 0; i < 16; ++i) g[i] = gate[i];
  int t = threadIdx.x;  // 256
  int o = blockIdx.x;   // outer bits {19,18,15,14,11,10,7,6}
  int base = ((o >> 6) & 3) * 262144 + ((o >> 4) & 3) * 16384 +
             ((o >> 2) & 3) * 1024 + (o & 3) * 64;
#pragma unroll
  for (int i = 0; i < 4; ++i) {
    int f = (i * 256 + t) * 4;
    int w = f & 63, c = (f >> 6) & 3, b = (f >> 8) & 3, a = (f >> 10) & 3;
    *(float4*)(s + PAD(f)) =
        *(const float4*)(psi + base + a * 65536 + b * 4096 + c * 256 + w);
  }
  __syncthreads();
  if (t < 128) {  // row 2: slab bits {11,9,7,5,1}
    int b2 = ((t >> 6) & 1) * 1024 + ((t >> 5) & 1) * 256 + ((t >> 4) & 1) * 64 +
             ((t >> 3) & 1) * 16 + ((t >> 2) & 1) * 8 + ((t >> 1) & 1) * 4 + (t & 1);
    hxf<2048, 512, 128, 32, 2>(s, g, b2);
  }
  __syncthreads();
  if (t < 128) {  // row 3: slab bits {10,8,6,4,0}
    int b3 = ((t >> 6) & 1) * 2048 + ((t >> 5) & 1) * 512 + ((t >> 4) & 1) * 128 +
             ((t >> 3) & 1) * 32 + ((t & 7) << 1);
    hxf<1024, 256, 64, 16, 1>(s, g, b3);
  }
  __syncthreads();
#pragma unroll
  for (int i = 0; i < 4; ++i) {
    int f = (i * 256 + t) * 4;
    int w = f & 63, c = (f >> 6) & 3, b = (f >> 8) & 3, a = (f >> 10) & 3;
    *(float4*)(psi + base + a * 65536 + b * 4096 + c * 256 + w) =
        *(const float4*)(s + PAD(f));
  }
}

// H phase B: rows 0,1 + V col 4 ; slab bits {19,18,15,14,11,10,7,6,3..0}
__global__ __launch_bounds__(256) void k_hb(float* __restrict__ psi,
                                            const float* __restrict__ gate) {
  __shared__ float s[5120];
  float g[16];
#pragma unroll
  for (int i = 0; i < 16; ++i) g[i] = gate[i];
  int t = threadIdx.x;  // 256
  int o = blockIdx.x;   // outer bits {17,16,13,12,9,8,5,4}
  int base = ((o >> 6) & 3) * 65536 + ((o >> 4) & 3) * 4096 +
             ((o >> 2) & 3) * 256 + (o & 3) * 16;
#pragma unroll
  for (int i = 0; i < 4; ++i) {
    int f = (i * 256 + t) * 4;
    int w = f & 15, d = (f >> 4) & 3, c = (f >> 6) & 3, b = (f >> 8) & 3,
        a = (f >> 10) & 3;
    *(float4*)(s + PAD(f)) = *(const float4*)(psi + base + a * 262144 +
                                              b * 16384 + c * 1024 + d * 64 + w);
  }
  __syncthreads();
  if (t < 128) {  // row 0: slab bits {11,9,7,5,3}
    int b0 = ((t >> 6) & 1) * 1024 + ((t >> 5) & 1) * 256 + ((t >> 4) & 1) * 64 +
             ((t >> 3) & 1) * 16 + ((t >> 2) & 1) * 4 + (t & 3);
    hxf<2048, 512, 128, 32, 8>(s, g, b0);
  }
  __syncthreads();
  if (t < 128) {  // row 1: slab bits {10,8,6,4,2}
    int b1 = ((t >> 6) & 1) * 2048 + ((t >> 5) & 1) * 512 + ((t >> 4) & 1) * 128 +
             ((t >> 3) & 1) * 32 + ((t >> 2) & 1) * 8 + (t & 3);
    hxf<1024, 256, 64, 16, 4>(s, g, b1);
  }
  __syncthreads();
  // V col 4 (slab bits 3..0): all H for col-4 qubits is complete here.
  vxf<1>(s, g, t * 16);
  __syncthreads();
#pragma unroll
  for (int i = 0; i < 4; ++i) {
    int f = (i * 256 + t) * 4;
    int w = f & 15, d = (f >> 4) & 3, c = (f >> 6) & 3, b = (f >> 8) & 3,
        a = (f >> 10) & 3;
    *(float4*)(psi + base + a * 262144 + b * 16384 + c * 1024 + d * 64 + w) =
        *(const float4*)(s + PAD(f));
  }
}

// V phase A: cols c2,c3 (bits 11..4; slab bits 11..0)
__global__ __launch_bounds__(256) void k_va(float* __restrict__ psi,
                                            const float* __restrict__ gate) {
  __shared__ float s[5120];
  float g[16];
#pragma unroll
  for (int i = 0; i < 16; ++i) g[i] = gate[i];
  int t = threadIdx.x;
  int base = blockIdx.x * 4096;
#pragma unroll
  for (int i = 0; i < 4; ++i) {
    int f = (i * 256 + t) * 4;
    *(float4*)(s + PAD(f)) = *(const float4*)(psi + base + f);
  }
  __syncthreads();
  vxf<16>(s, g, ((t >> 4) << 8) | (t & 15));     // c3
  __syncthreads();
  vxf<256>(s, g, t);                             // c2
  __syncthreads();
#pragma unroll
  for (int i = 0; i < 4; ++i) {
    int f = (i * 256 + t) * 4;
    *(float4*)(psi + base + f) = *(const float4*)(s + PAD(f));
  }
}

// V phase B: cols c0,c1 (bits 19..12) ; slab bits {19..12, 3..0}
// GATHER=true on the final iteration: each block emits outputs in its slab.
template <bool GATHER>
__global__ __launch_bounds__(256) void k_vb(float* __restrict__ psi,
                                            const float* __restrict__ gate,
                                            const int* __restrict__ x,
                                            float* __restrict__ out) {
  __shared__ float s[5120];
  float g[16];
#pragma unroll
  for (int i = 0; i < 16; ++i) g[i] = gate[i];
  int t = threadIdx.x;
  int o = blockIdx.x;  // bits 11..4
#pragma unroll
  for (int i = 0; i < 4; ++i) {
    int f = (i * 256 + t) * 4;
    int h = f >> 4, w = f & 15;
    *(float4*)(s + PAD(f)) = *(const float4*)(psi + h * 4096 + o * 16 + w);
  }
  __syncthreads();
  vxf<256>(s, g, t);                             // c0 (slab bits 11..8)
  __syncthreads();
  vxf<16>(s, g, ((t >> 4) << 8) | (t & 15));     // c1 (slab bits 7..4)
  __syncthreads();
  if (GATHER && t < 64) {
    int idx = 0;
#pragma unroll
    for (int q = 0; q < 20; ++q) {
      int i = q / 5, j = q % 5;
      idx |= x[t * 20 + q] << (19 - 4 * j - i);
    }
    if (((idx >> 4) & 255) == o)
      out[t] = s[PAD(((idx >> 12) << 4) | (idx & 15))];
  }
#pragma unroll
  for (int i = 0; i < 4; ++i) {
    int f = (i * 256 + t) * 4;
    int h = f >> 4, w = f & 15;
    *(float4*)(psi + h * 4096 + o * 16 + w) = *(const float4*)(s + PAD(f));
  }
}

// ---------------------------------------------------------------------------
extern "C" void kernel_launch(void* const* d_in, const int* in_sizes, int n_in,
                              void* d_out, int out_size, void* d_ws, size_t ws_size,
                              hipStream_t stream) {
  const int* x = (const int*)d_in[0];
  const float* peps = (const float*)d_in[1];
  const float* gate = (const float*)d_in[2];
  float* ws = (float*)d_ws;
  float* psi = ws + PSIO;
  float* out = (float*)d_out;

  k_build_cols<<<386, 256, 0, stream>>>(peps, ws);
  k_small<<<320, 256, 0, stream>>>(ws, ws + M01TO, ws + M34TO);
  k_t012<<<256, 256, 0, stream>>>(ws + M01TO, ws + COL2, ws + T12TO);
  k_psi0<<<256, 256, 0, stream>>>(ws + T12TO, ws + M34TO, psi);
  for (int it = 0; it < 5; ++it) {
    k_ha<<<256, 256, 0, stream>>>(psi, gate);
    k_hb<<<256, 256, 0, stream>>>(psi, gate);
    k_va<<<256, 256, 0, stream>>>(psi, gate);
    if (it < 4)
      k_vb<false><<<256, 256, 0, stream>>>(psi, gate, x, out);
    else
      k_vb<true><<<256, 256, 0, stream>>>(psi, gate, x, out);
  }
}